// Round 1
// baseline (1377.717 us; speedup 1.0000x reference)
//
#include <hip/hip_runtime.h>

#define NN 50000
#define NE 800000
// D = 64, H = 128, KE = 3*D = 192

__device__ __forceinline__ float f4c(const float4& v, int u) {
    return u == 0 ? v.x : (u == 1 ? v.y : (u == 2 ? v.z : v.w));
}

// ---------------- Edge kernel: 64 edges per block, 256 threads ----------------
// xs[64][196] holds gathered [edge | node_recv | node_send] (192 floats, pad 4)
// GEMM1: [64,192] @ We1[192,128] -> relu -> hs[64][132] (aliases xs)
// GEMM2: [64,128] @ We2[128,64] -> atomicAdd into agg[receiver]
__global__ __launch_bounds__(256) void edge_kernel(
    const float* __restrict__ nodes, const float* __restrict__ edges,
    const float* __restrict__ We1, const float* __restrict__ be1,
    const float* __restrict__ We2, const float* __restrict__ be2,
    const int* __restrict__ senders, const int* __restrict__ receivers,
    float* __restrict__ agg)
{
    __shared__ float xs[64][196];   // 50176 B; reused as hs (stride 132)
    __shared__ float wc[16 * 128];  // 8192 B weight chunk (also wc2[16][64])
    __shared__ int ridx[64];
    __shared__ int sidx[64];

    const int t = threadIdx.x;
    const int e0 = blockIdx.x * 64;

    if (t < 64) { ridx[t] = receivers[e0 + t]; sidx[t] = senders[e0 + t]; }
    __syncthreads();

    // gather input tile: 64 edges * 48 float4
    #pragma unroll
    for (int i = 0; i < 12; ++i) {
        int flat = t + 256 * i;        // 0..3071
        int m = flat / 48;
        int q = flat % 48;
        int col4 = (q & 15) * 4;
        const float* src;
        int dst;
        if (q < 16)      { src = edges + (size_t)(e0 + m) * 64 + col4; dst = col4; }
        else if (q < 32) { src = nodes + (size_t)ridx[m] * 64 + col4;  dst = 64 + col4; }
        else             { src = nodes + (size_t)sidx[m] * 64 + col4;  dst = 128 + col4; }
        *(float4*)&xs[m][dst] = *(const float4*)src;
    }
    __syncthreads();

    const int tc = t & 15;   // col group
    const int tr = t >> 4;   // row group
    const int j0 = tc * 8;   // 8 H-columns
    const int m0 = tr * 4;   // 4 edges

    float acc[4][8];
    #pragma unroll
    for (int r = 0; r < 4; ++r)
        #pragma unroll
        for (int c = 0; c < 8; ++c) acc[r][c] = 0.f;

    // GEMM1: K = 192 in chunks of 16
    for (int k0 = 0; k0 < 192; k0 += 16) {
        #pragma unroll
        for (int i = 0; i < 2; ++i) {
            int fidx = t + 256 * i;         // 0..511 float4
            int row = fidx >> 5;            // 32 float4 per row of 128
            int c4 = (fidx & 31) * 4;
            *(float4*)&wc[row * 128 + c4] = *(const float4*)&We1[(size_t)(k0 + row) * 128 + c4];
        }
        __syncthreads();
        #pragma unroll
        for (int kk = 0; kk < 16; kk += 4) {
            float4 a[4];
            #pragma unroll
            for (int r = 0; r < 4; ++r) a[r] = *(const float4*)&xs[m0 + r][k0 + kk];
            #pragma unroll
            for (int u = 0; u < 4; ++u) {
                float4 b0 = *(const float4*)&wc[(kk + u) * 128 + j0];
                float4 b1 = *(const float4*)&wc[(kk + u) * 128 + j0 + 4];
                #pragma unroll
                for (int r = 0; r < 4; ++r) {
                    float av = f4c(a[r], u);
                    acc[r][0] += av * b0.x; acc[r][1] += av * b0.y;
                    acc[r][2] += av * b0.z; acc[r][3] += av * b0.w;
                    acc[r][4] += av * b1.x; acc[r][5] += av * b1.y;
                    acc[r][6] += av * b1.z; acc[r][7] += av * b1.w;
                }
            }
        }
        __syncthreads();
    }

    // bias + relu -> hs (aliases xs, stride 132)
    float* hsf = &xs[0][0];
    #pragma unroll
    for (int r = 0; r < 4; ++r) {
        #pragma unroll
        for (int c = 0; c < 8; ++c) {
            float v = acc[r][c] + be1[j0 + c];
            hsf[(m0 + r) * 132 + j0 + c] = fmaxf(v, 0.f);
        }
    }
    __syncthreads();

    // GEMM2: [64,128] @ We2[128,64]
    const int c0 = tc * 4;
    float acc2[4][4];
    #pragma unroll
    for (int r = 0; r < 4; ++r)
        #pragma unroll
        for (int c = 0; c < 4; ++c) acc2[r][c] = 0.f;

    for (int k0 = 0; k0 < 128; k0 += 16) {
        {
            int row = t >> 4;               // 16 float4 per row of 64
            int c4 = (t & 15) * 4;
            *(float4*)&wc[row * 64 + c4] = *(const float4*)&We2[(size_t)(k0 + row) * 64 + c4];
        }
        __syncthreads();
        #pragma unroll
        for (int kk = 0; kk < 16; kk += 4) {
            float4 a[4];
            #pragma unroll
            for (int r = 0; r < 4; ++r) a[r] = *(const float4*)&hsf[(m0 + r) * 132 + k0 + kk];
            #pragma unroll
            for (int u = 0; u < 4; ++u) {
                float4 b = *(const float4*)&wc[(kk + u) * 64 + c0];
                #pragma unroll
                for (int r = 0; r < 4; ++r) {
                    float av = f4c(a[r], u);
                    acc2[r][0] += av * b.x; acc2[r][1] += av * b.y;
                    acc2[r][2] += av * b.z; acc2[r][3] += av * b.w;
                }
            }
        }
        __syncthreads();
    }

    // scatter-add into agg
    #pragma unroll
    for (int r = 0; r < 4; ++r) {
        int node = ridx[m0 + r];
        float* dst = agg + (size_t)node * 64 + c0;
        #pragma unroll
        for (int c = 0; c < 4; ++c)
            atomicAdd(dst + c, acc2[r][c] + be2[c0 + c]);
    }
}

// ---------------- Node kernel: 64 nodes per block, 256 threads ----------------
__global__ __launch_bounds__(256) void node_kernel(
    const float* __restrict__ nodes, const float* __restrict__ agg,
    const float* __restrict__ Wn1, const float* __restrict__ bn1,
    const float* __restrict__ Wn2, const float* __restrict__ bn2,
    float* __restrict__ out)
{
    __shared__ float xs[64][132];   // [agg | node] (128 floats, pad 4); reused as hs
    __shared__ float wc[16 * 128];

    const int t = threadIdx.x;
    const int n0 = blockIdx.x * 64;

    // load input tile: 64 nodes * 32 float4
    #pragma unroll
    for (int i = 0; i < 8; ++i) {
        int flat = t + 256 * i;        // 0..2047
        int m = flat >> 5;
        int q = flat & 31;
        int col4 = (q & 15) * 4;
        int n = n0 + m;
        float4 v = make_float4(0.f, 0.f, 0.f, 0.f);
        if (n < NN) {
            v = (q < 16) ? *(const float4*)&agg[(size_t)n * 64 + col4]
                         : *(const float4*)&nodes[(size_t)n * 64 + col4];
        }
        int dst = (q < 16) ? col4 : 64 + col4;
        *(float4*)&xs[m][dst] = v;
    }
    __syncthreads();

    const int tc = t & 15;
    const int tr = t >> 4;
    const int j0 = tc * 8;
    const int m0 = tr * 4;

    float acc[4][8];
    #pragma unroll
    for (int r = 0; r < 4; ++r)
        #pragma unroll
        for (int c = 0; c < 8; ++c) acc[r][c] = 0.f;

    for (int k0 = 0; k0 < 128; k0 += 16) {
        #pragma unroll
        for (int i = 0; i < 2; ++i) {
            int fidx = t + 256 * i;
            int row = fidx >> 5;
            int c4 = (fidx & 31) * 4;
            *(float4*)&wc[row * 128 + c4] = *(const float4*)&Wn1[(size_t)(k0 + row) * 128 + c4];
        }
        __syncthreads();
        #pragma unroll
        for (int kk = 0; kk < 16; kk += 4) {
            float4 a[4];
            #pragma unroll
            for (int r = 0; r < 4; ++r) a[r] = *(const float4*)&xs[m0 + r][k0 + kk];
            #pragma unroll
            for (int u = 0; u < 4; ++u) {
                float4 b0 = *(const float4*)&wc[(kk + u) * 128 + j0];
                float4 b1 = *(const float4*)&wc[(kk + u) * 128 + j0 + 4];
                #pragma unroll
                for (int r = 0; r < 4; ++r) {
                    float av = f4c(a[r], u);
                    acc[r][0] += av * b0.x; acc[r][1] += av * b0.y;
                    acc[r][2] += av * b0.z; acc[r][3] += av * b0.w;
                    acc[r][4] += av * b1.x; acc[r][5] += av * b1.y;
                    acc[r][6] += av * b1.z; acc[r][7] += av * b1.w;
                }
            }
        }
        __syncthreads();
    }

    float* hsf = &xs[0][0];
    #pragma unroll
    for (int r = 0; r < 4; ++r) {
        #pragma unroll
        for (int c = 0; c < 8; ++c) {
            float v = acc[r][c] + bn1[j0 + c];
            hsf[(m0 + r) * 132 + j0 + c] = fmaxf(v, 0.f);
        }
    }
    __syncthreads();

    const int c0 = tc * 4;
    float acc2[4][4];
    #pragma unroll
    for (int r = 0; r < 4; ++r)
        #pragma unroll
        for (int c = 0; c < 4; ++c) acc2[r][c] = 0.f;

    for (int k0 = 0; k0 < 128; k0 += 16) {
        {
            int row = t >> 4;
            int c4 = (t & 15) * 4;
            *(float4*)&wc[row * 64 + c4] = *(const float4*)&Wn2[(size_t)(k0 + row) * 64 + c4];
        }
        __syncthreads();
        #pragma unroll
        for (int kk = 0; kk < 16; kk += 4) {
            float4 a[4];
            #pragma unroll
            for (int r = 0; r < 4; ++r) a[r] = *(const float4*)&hsf[(m0 + r) * 132 + k0 + kk];
            #pragma unroll
            for (int u = 0; u < 4; ++u) {
                float4 b = *(const float4*)&wc[(kk + u) * 64 + c0];
                #pragma unroll
                for (int r = 0; r < 4; ++r) {
                    float av = f4c(a[r], u);
                    acc2[r][0] += av * b.x; acc2[r][1] += av * b.y;
                    acc2[r][2] += av * b.z; acc2[r][3] += av * b.w;
                }
            }
        }
        __syncthreads();
    }

    #pragma unroll
    for (int r = 0; r < 4; ++r) {
        int n = n0 + m0 + r;
        if (n < NN) {
            float4 v;
            v.x = acc2[r][0] + bn2[c0 + 0];
            v.y = acc2[r][1] + bn2[c0 + 1];
            v.z = acc2[r][2] + bn2[c0 + 2];
            v.w = acc2[r][3] + bn2[c0 + 3];
            *(float4*)&out[(size_t)n * 64 + c0] = v;
        }
    }
}

extern "C" void kernel_launch(void* const* d_in, const int* in_sizes, int n_in,
                              void* d_out, int out_size, void* d_ws, size_t ws_size,
                              hipStream_t stream) {
    const float* nodes = (const float*)d_in[0];
    const float* edges = (const float*)d_in[1];
    const float* We1   = (const float*)d_in[2];
    const float* be1   = (const float*)d_in[3];
    const float* We2   = (const float*)d_in[4];
    const float* be2   = (const float*)d_in[5];
    const float* Wn1   = (const float*)d_in[6];
    const float* bn1   = (const float*)d_in[7];
    const float* Wn2   = (const float*)d_in[8];
    const float* bn2   = (const float*)d_in[9];
    const int* senders   = (const int*)d_in[10];
    const int* receivers = (const int*)d_in[11];
    float* out = (float*)d_out;
    float* agg = (float*)d_ws;   // [NN, 64] fp32 = 12.8 MB

    hipMemsetAsync(agg, 0, (size_t)NN * 64 * sizeof(float), stream);
    edge_kernel<<<NE / 64, 256, 0, stream>>>(nodes, edges, We1, be1, We2, be2,
                                             senders, receivers, agg);
    node_kernel<<<(NN + 63) / 64, 256, 0, stream>>>(nodes, agg, Wn1, bn1, Wn2, bn2, out);
}

// Round 2
// 462.951 us; speedup vs baseline: 2.9759x; 2.9759x over previous
//
#include <hip/hip_runtime.h>

#define NN 50000
#define NE 800000

typedef __attribute__((ext_vector_type(8))) short bf16x8;
typedef __attribute__((ext_vector_type(8))) unsigned short us8;
typedef __attribute__((ext_vector_type(4))) unsigned short us4;
typedef __attribute__((ext_vector_type(4))) float f32x4;

#define MFMA16 __builtin_amdgcn_mfma_f32_16x16x32_bf16

__device__ __forceinline__ unsigned short f2b(float f) {
    union { float f; unsigned int u; } x; x.f = f;
    unsigned int r = x.u + 0x7FFFu + ((x.u >> 16) & 1u);
    return (unsigned short)(r >> 16);
}

// ---------------- prep: convert nodes to bf16; convert+transpose weights ----------------
__global__ __launch_bounds__(256) void prep_kernel(
    const float* __restrict__ nodes,
    const float* __restrict__ We1, const float* __restrict__ We2,
    const float* __restrict__ Wn1, const float* __restrict__ Wn2,
    unsigned short* __restrict__ nodes_bf,
    unsigned short* __restrict__ We1T, unsigned short* __restrict__ We2T,
    unsigned short* __restrict__ Wn1T, unsigned short* __restrict__ Wn2T)
{
    const int b = blockIdx.x, t = threadIdx.x;
    if (b < 400) {
        const float4* src = (const float4*)nodes;
        for (int i = b * 256 + t; i < NN * 16; i += 400 * 256) {
            float4 v = src[i];
            us4 o; o[0] = f2b(v.x); o[1] = f2b(v.y); o[2] = f2b(v.z); o[3] = f2b(v.w);
            *(us4*)&nodes_bf[(size_t)i * 4] = o;
        }
    } else {
        const int base = (b - 400) * 256 + t;
        for (int idx = base; idx < 57344; idx += 16 * 256) {
            if (idx < 24576) {               // We1T[128][192] <- We1[192][128]
                int n = idx / 192, k = idx % 192;
                We1T[idx] = f2b(We1[k * 128 + n]);
            } else if (idx < 32768) {        // We2T[64][128] <- We2[128][64]
                int j = idx - 24576; int n = j / 128, k = j % 128;
                We2T[j] = f2b(We2[k * 64 + n]);
            } else if (idx < 49152) {        // Wn1T[128][128] <- Wn1[128][128]
                int j = idx - 32768; int n = j / 128, k = j % 128;
                Wn1T[j] = f2b(Wn1[k * 128 + n]);
            } else {                         // Wn2T[64][128] <- Wn2[128][64]
                int j = idx - 49152; int n = j / 128, k = j % 128;
                Wn2T[j] = f2b(Wn2[k * 64 + n]);
            }
        }
    }
}

// ---------------- edge kernel: 64 edges/block, 4 waves, MFMA ----------------
// xs[64][200] bf16 gathered input (192 valid); hs aliases xs with stride 136.
// wbT[n][40] weight chunk, transposed, 32 valid k per chunk.
__global__ __launch_bounds__(256, 4) void edge_kernel(
    const unsigned short* __restrict__ nodes_bf, const float* __restrict__ edges,
    const unsigned short* __restrict__ We1T, const float* __restrict__ be1,
    const unsigned short* __restrict__ We2T, const float* __restrict__ be2,
    const int* __restrict__ senders, const int* __restrict__ receivers,
    float* __restrict__ agg)
{
    __shared__ unsigned short xs[64 * 200];   // 25.6 KB (hs aliases: stride 136)
    __shared__ unsigned short wb[128 * 40];   // 10.0 KB
    __shared__ int ridx[64];
    __shared__ int sidx[64];

    const int t = threadIdx.x;
    const int e0 = blockIdx.x * 64;
    const int w = t >> 6;        // wave 0..3
    const int l = t & 63;
    const int lc = l & 15;       // lane col
    const int lq = l >> 4;       // quad

    if (t < 64) { ridx[t] = receivers[e0 + t]; sidx[t] = senders[e0 + t]; }
    __syncthreads();

    // gather edges (fp32 -> bf16)
    #pragma unroll
    for (int i = 0; i < 4; ++i) {
        int idx = t + 256 * i;            // 0..1023
        int m = idx >> 4, q = idx & 15;
        float4 v = *(const float4*)&edges[((size_t)(e0 + m)) * 64 + q * 4];
        us4 o; o[0] = f2b(v.x); o[1] = f2b(v.y); o[2] = f2b(v.z); o[3] = f2b(v.w);
        *(us4*)&xs[m * 200 + q * 4] = o;
    }
    // gather receiver node feats (bf16 copy)
    #pragma unroll
    for (int i = 0; i < 2; ++i) {
        int idx = t + 256 * i;            // 0..511
        int m = idx >> 3, q = idx & 7;
        us8 v = *(const us8*)&nodes_bf[(size_t)ridx[m] * 64 + q * 8];
        *(us8*)&xs[m * 200 + 64 + q * 8] = v;
    }
    // gather sender node feats
    #pragma unroll
    for (int i = 0; i < 2; ++i) {
        int idx = t + 256 * i;
        int m = idx >> 3, q = idx & 7;
        us8 v = *(const us8*)&nodes_bf[(size_t)sidx[m] * 64 + q * 8];
        *(us8*)&xs[m * 200 + 128 + q * 8] = v;
    }
    __syncthreads();

    // GEMM1: [64,192] @ We1[192,128]; wave w -> N cols [w*32, w*32+32), all 4 M tiles
    f32x4 acc[4][2];
    #pragma unroll
    for (int mt = 0; mt < 4; ++mt) { acc[mt][0] = (f32x4)0.f; acc[mt][1] = (f32x4)0.f; }

    for (int c = 0; c < 6; ++c) {
        const int k0 = 32 * c;
        #pragma unroll
        for (int i = 0; i < 2; ++i) {
            int idx = t + 256 * i;        // 0..511
            int n = idx >> 2, cc = idx & 3;
            *(us8*)&wb[n * 40 + cc * 8] = *(const us8*)&We1T[n * 192 + k0 + cc * 8];
        }
        __syncthreads();
        bf16x8 b0 = *(const bf16x8*)&wb[(w * 32 + lc) * 40 + lq * 8];
        bf16x8 b1 = *(const bf16x8*)&wb[(w * 32 + 16 + lc) * 40 + lq * 8];
        #pragma unroll
        for (int mt = 0; mt < 4; ++mt) {
            bf16x8 a = *(const bf16x8*)&xs[(mt * 16 + lc) * 200 + k0 + lq * 8];
            acc[mt][0] = MFMA16(a, b0, acc[mt][0], 0, 0, 0);
            acc[mt][1] = MFMA16(a, b1, acc[mt][1], 0, 0, 0);
        }
        __syncthreads();
    }

    // bias + relu -> hs (aliases xs, stride 136)
    #pragma unroll
    for (int nt = 0; nt < 2; ++nt) {
        int col = w * 32 + nt * 16 + lc;
        float bias = be1[col];
        #pragma unroll
        for (int mt = 0; mt < 4; ++mt) {
            #pragma unroll
            for (int r = 0; r < 4; ++r) {
                int row = mt * 16 + lq * 4 + r;
                float v = fmaxf(acc[mt][nt][r] + bias, 0.f);
                xs[row * 136 + col] = f2b(v);
            }
        }
    }
    __syncthreads();

    // GEMM2: [64,128] @ We2[128,64]; wave w -> N cols [w*16, w*16+16)
    f32x4 acc2[4];
    #pragma unroll
    for (int mt = 0; mt < 4; ++mt) acc2[mt] = (f32x4)0.f;

    for (int c = 0; c < 4; ++c) {
        const int k0 = 32 * c;
        {
            int n = t >> 2, cc = t & 3;   // 64 rows x 4 chunks
            *(us8*)&wb[n * 40 + cc * 8] = *(const us8*)&We2T[n * 128 + k0 + cc * 8];
        }
        __syncthreads();
        bf16x8 b = *(const bf16x8*)&wb[(w * 16 + lc) * 40 + lq * 8];
        #pragma unroll
        for (int mt = 0; mt < 4; ++mt) {
            bf16x8 a = *(const bf16x8*)&xs[(mt * 16 + lc) * 136 + k0 + lq * 8];
            acc2[mt] = MFMA16(a, b, acc2[mt], 0, 0, 0);
        }
        __syncthreads();
    }

    // scatter-add
    const int col = w * 16 + lc;
    const float bias2 = be2[col];
    #pragma unroll
    for (int mt = 0; mt < 4; ++mt) {
        #pragma unroll
        for (int r = 0; r < 4; ++r) {
            int row = mt * 16 + lq * 4 + r;
            atomicAdd(&agg[(size_t)ridx[row] * 64 + col], acc2[mt][r] + bias2);
        }
    }
}

// ---------------- node kernel: 64 nodes/block, 4 waves, MFMA ----------------
__global__ __launch_bounds__(256, 4) void node_kernel(
    const unsigned short* __restrict__ nodes_bf, const float* __restrict__ agg,
    const unsigned short* __restrict__ Wn1T, const float* __restrict__ bn1,
    const unsigned short* __restrict__ Wn2T, const float* __restrict__ bn2,
    float* __restrict__ out)
{
    __shared__ unsigned short xs[64 * 136];   // input [agg|node] and hs (both stride 136)
    __shared__ unsigned short wb[128 * 40];

    const int t = threadIdx.x;
    const int n0 = blockIdx.x * 64;
    const int w = t >> 6;
    const int l = t & 63;
    const int lc = l & 15;
    const int lq = l >> 4;

    // stage agg (fp32 -> bf16), cols 0..63
    #pragma unroll
    for (int i = 0; i < 4; ++i) {
        int idx = t + 256 * i;
        int m = idx >> 4, q = idx & 15;
        int n = n0 + m;
        float4 v = make_float4(0.f, 0.f, 0.f, 0.f);
        if (n < NN) v = *(const float4*)&agg[(size_t)n * 64 + q * 4];
        us4 o; o[0] = f2b(v.x); o[1] = f2b(v.y); o[2] = f2b(v.z); o[3] = f2b(v.w);
        *(us4*)&xs[m * 136 + q * 4] = o;
    }
    // stage node feats (bf16), cols 64..127
    #pragma unroll
    for (int i = 0; i < 2; ++i) {
        int idx = t + 256 * i;
        int m = idx >> 3, q = idx & 7;
        int n = n0 + m;
        us8 v = {0, 0, 0, 0, 0, 0, 0, 0};
        if (n < NN) v = *(const us8*)&nodes_bf[(size_t)n * 64 + q * 8];
        *(us8*)&xs[m * 136 + 64 + q * 8] = v;
    }
    __syncthreads();

    // GEMM1: [64,128] @ Wn1[128,128]
    f32x4 acc[4][2];
    #pragma unroll
    for (int mt = 0; mt < 4; ++mt) { acc[mt][0] = (f32x4)0.f; acc[mt][1] = (f32x4)0.f; }

    for (int c = 0; c < 4; ++c) {
        const int k0 = 32 * c;
        #pragma unroll
        for (int i = 0; i < 2; ++i) {
            int idx = t + 256 * i;
            int n = idx >> 2, cc = idx & 3;
            *(us8*)&wb[n * 40 + cc * 8] = *(const us8*)&Wn1T[n * 128 + k0 + cc * 8];
        }
        __syncthreads();
        bf16x8 b0 = *(const bf16x8*)&wb[(w * 32 + lc) * 40 + lq * 8];
        bf16x8 b1 = *(const bf16x8*)&wb[(w * 32 + 16 + lc) * 40 + lq * 8];
        #pragma unroll
        for (int mt = 0; mt < 4; ++mt) {
            bf16x8 a = *(const bf16x8*)&xs[(mt * 16 + lc) * 136 + k0 + lq * 8];
            acc[mt][0] = MFMA16(a, b0, acc[mt][0], 0, 0, 0);
            acc[mt][1] = MFMA16(a, b1, acc[mt][1], 0, 0, 0);
        }
        __syncthreads();
    }

    // bias + relu -> hs (same region, stride 136)
    #pragma unroll
    for (int nt = 0; nt < 2; ++nt) {
        int col = w * 32 + nt * 16 + lc;
        float bias = bn1[col];
        #pragma unroll
        for (int mt = 0; mt < 4; ++mt) {
            #pragma unroll
            for (int r = 0; r < 4; ++r) {
                int row = mt * 16 + lq * 4 + r;
                float v = fmaxf(acc[mt][nt][r] + bias, 0.f);
                xs[row * 136 + col] = f2b(v);
            }
        }
    }
    __syncthreads();

    // GEMM2: [64,128] @ Wn2[128,64]
    f32x4 acc2[4];
    #pragma unroll
    for (int mt = 0; mt < 4; ++mt) acc2[mt] = (f32x4)0.f;

    for (int c = 0; c < 4; ++c) {
        const int k0 = 32 * c;
        {
            int n = t >> 2, cc = t & 3;
            *(us8*)&wb[n * 40 + cc * 8] = *(const us8*)&Wn2T[n * 128 + k0 + cc * 8];
        }
        __syncthreads();
        bf16x8 b = *(const bf16x8*)&wb[(w * 16 + lc) * 40 + lq * 8];
        #pragma unroll
        for (int mt = 0; mt < 4; ++mt) {
            bf16x8 a = *(const bf16x8*)&xs[(mt * 16 + lc) * 136 + k0 + lq * 8];
            acc2[mt] = MFMA16(a, b, acc2[mt], 0, 0, 0);
        }
        __syncthreads();
    }

    const int col = w * 16 + lc;
    const float bias2 = bn2[col];
    #pragma unroll
    for (int mt = 0; mt < 4; ++mt) {
        #pragma unroll
        for (int r = 0; r < 4; ++r) {
            int row = mt * 16 + lq * 4 + r;
            int n = n0 + row;
            if (n < NN) out[(size_t)n * 64 + col] = acc2[mt][r] + bias2;
        }
    }
}

extern "C" void kernel_launch(void* const* d_in, const int* in_sizes, int n_in,
                              void* d_out, int out_size, void* d_ws, size_t ws_size,
                              hipStream_t stream) {
    const float* nodes = (const float*)d_in[0];
    const float* edges = (const float*)d_in[1];
    const float* We1   = (const float*)d_in[2];
    const float* be1   = (const float*)d_in[3];
    const float* We2   = (const float*)d_in[4];
    const float* be2   = (const float*)d_in[5];
    const float* Wn1   = (const float*)d_in[6];
    const float* bn1   = (const float*)d_in[7];
    const float* Wn2   = (const float*)d_in[8];
    const float* bn2   = (const float*)d_in[9];
    const int* senders   = (const int*)d_in[10];
    const int* receivers = (const int*)d_in[11];
    float* out = (float*)d_out;

    // ws layout (bytes)
    char* ws = (char*)d_ws;
    float* agg = (float*)ws;                                    // 12,800,000 B
    unsigned short* nodes_bf = (unsigned short*)(ws + 12800000); //  6,400,000 B
    unsigned short* We1T = (unsigned short*)(ws + 19200000);     //     49,152 B
    unsigned short* We2T = (unsigned short*)(ws + 19249152);     //     16,384 B
    unsigned short* Wn1T = (unsigned short*)(ws + 19265536);     //     32,768 B
    unsigned short* Wn2T = (unsigned short*)(ws + 19298304);     //     16,384 B

    hipMemsetAsync(agg, 0, (size_t)NN * 64 * sizeof(float), stream);
    prep_kernel<<<416, 256, 0, stream>>>(nodes, We1, We2, Wn1, Wn2,
                                         nodes_bf, We1T, We2T, Wn1T, Wn2T);
    edge_kernel<<<NE / 64, 256, 0, stream>>>(nodes_bf, edges, We1T, be1, We2T, be2,
                                             senders, receivers, agg);
    node_kernel<<<(NN + 63) / 64, 256, 0, stream>>>(nodes_bf, agg, Wn1T, bn1, Wn2T, bn2, out);
}